// Round 9
// baseline (331.928 us; speedup 1.0000x reference)
//
#include <hip/hip_runtime.h>

typedef short s16x8 __attribute__((ext_vector_type(8)));
typedef float f32x4 __attribute__((ext_vector_type(4)));

__device__ __forceinline__ unsigned short f2bf(float f) {
    union { float f; unsigned u; } v; v.f = f;
    return (unsigned short)((v.u + 0x7FFFu + ((v.u >> 16) & 1u)) >> 16);
}
__device__ __forceinline__ float bf2f(unsigned short h) {
    union { unsigned u; float f; } v; v.u = ((unsigned)h) << 16;
    return v.f;
}

// Pure execution-sync barrier (no waitcnt): bounds wave drift for L2 locality.
__device__ __forceinline__ void soft_barrier() {
    __builtin_amdgcn_sched_barrier(0);
    __builtin_amdgcn_s_barrier();
    __builtin_amdgcn_sched_barrier(0);
}

#define NBLK 2048   // 16384 positions / 8 per block

// ---------- prep: W1 (512x256 f32) -> W1T bf16 [16][256][32]; Wf -> WfT bf16 [8][256][32] ----------
__global__ void prep_weights(const float* __restrict__ W1, const float* __restrict__ Wf,
                             unsigned short* __restrict__ W1T, unsigned short* __restrict__ WfT) {
    int t = blockIdx.x * 256 + threadIdx.x;      // 131072 threads
    {   // W1T[t]: t = ((c*256)+n)*32 + kk
        int c  = t >> 13;
        int n  = (t >> 5) & 255;
        int kk = t & 31;
        W1T[t] = f2bf(W1[(c * 32 + kk) * 256 + n]);
    }
    if (t < 65536) {
        int c  = t >> 13;
        int n  = (t >> 5) & 255;
        int hh = t & 31;
        WfT[t] = f2bf(Wf[(c * 32 + hh) * 257 + n]);
    }
}

__global__ __launch_bounds__(512, 2)
void fused_embed(const float* __restrict__ net_in, const float* __restrict__ embeds,
                 const float* __restrict__ mg, const float* __restrict__ W1,
                 const float* __restrict__ b1, const float* __restrict__ Wf,
                 const float* __restrict__ bfv, const float* __restrict__ gam,
                 const float* __restrict__ bet, float* __restrict__ out,
                 const unsigned short* __restrict__ W1T, const unsigned short* __restrict__ WfT)
{
    // LDS: 66560 + 8448 + 8448 + 32 = 83488 B (>80KB -> 1 block/CU, the
    // validated envelope). GEMM1 uses NO LDS: each wave streams its own A rows
    // from global (cvt in-register) and W fragments from L2.
    __shared__ unsigned short Hbuf[128][260];     // H = relu(A@W1+b1), bf16 (520B rows)
    __shared__ unsigned short gbuf[16][264];      // g rows (8 used + 8 zero pad), bf16
    __shared__ float updb[8][264];                // updates (positions x 256), f32
    __shared__ float sbuf[8];                     // s_p = sum_k w_k m_k

    const int tid  = threadIdx.x;
    const int lane = tid & 63;
    const int wid  = tid >> 6;     // 0..7
    const int l15  = lane & 15;
    const int g8   = (lane >> 4) * 8;
    const int blk  = blockIdx.x;
    const int row0 = blk * 128;

    const f32x4 zero4 = {0.f, 0.f, 0.f, 0.f};

    // ========== GEMM1: per-wave streaming, barrier-free ==========
    // wave wid: wr=wid>>1 (rows [wr*32, +32)), wc=wid&1 (cols [wc*128, +128))
    const int wr = wid >> 1;
    const int wc = wid & 1;

    f32x4 acc[2][8];
    #pragma unroll
    for (int i = 0; i < 2; ++i)
        #pragma unroll
        for (int j = 0; j < 8; ++j)
            acc[i][j] = zero4;

    const float* pA0 = net_in + (row0 + wr * 32 + l15) * 512;       // i=0 row
    const float* pA1 = pA0 + 16 * 512;                              // i=1 row
    const int wbase = (wc * 128 + l15) * 32 + g8;                   // + j*512 per col-tile

    // 1-deep register prefetch slots (statically indexed — full unroll)
    float4 a0[2], a1[2], a2[2], a3[2];   // A: row-i0 lo/hi, row-i1 lo/hi
    s16x8  wf[2][8];                     // W: 8 B-fragments (16B each, L2)

#define S1_ISSUE(KC, S) do { \
        a0[S] = *(const float4*)(pA0 + (KC) * 32 + g8); \
        a1[S] = *(const float4*)(pA0 + (KC) * 32 + g8 + 4); \
        a2[S] = *(const float4*)(pA1 + (KC) * 32 + g8); \
        a3[S] = *(const float4*)(pA1 + (KC) * 32 + g8 + 4); \
        const unsigned short* _wp = W1T + (KC) * 8192 + wbase; \
        wf[S][0] = *(const s16x8*)(_wp); \
        wf[S][1] = *(const s16x8*)(_wp + 512); \
        wf[S][2] = *(const s16x8*)(_wp + 1024); \
        wf[S][3] = *(const s16x8*)(_wp + 1536); \
        wf[S][4] = *(const s16x8*)(_wp + 2048); \
        wf[S][5] = *(const s16x8*)(_wp + 2560); \
        wf[S][6] = *(const s16x8*)(_wp + 3072); \
        wf[S][7] = *(const s16x8*)(_wp + 3584); \
    } while (0)

    S1_ISSUE(0, 0);

    #pragma unroll
    for (int kc = 0; kc < 16; ++kc) {
        const int cur = kc & 1;
        if (kc < 15) S1_ISSUE(kc + 1, cur ^ 1);
        // cvt A slot -> bf16 fragments (identical rounding path to staged version)
        s16x8 af0, af1;
        {
            int4 p0, p1;
            asm("v_cvt_pk_bf16_f32 %0, %1, %2" : "=v"(p0.x) : "v"(a0[cur].x), "v"(a0[cur].y));
            asm("v_cvt_pk_bf16_f32 %0, %1, %2" : "=v"(p0.y) : "v"(a0[cur].z), "v"(a0[cur].w));
            asm("v_cvt_pk_bf16_f32 %0, %1, %2" : "=v"(p0.z) : "v"(a1[cur].x), "v"(a1[cur].y));
            asm("v_cvt_pk_bf16_f32 %0, %1, %2" : "=v"(p0.w) : "v"(a1[cur].z), "v"(a1[cur].w));
            asm("v_cvt_pk_bf16_f32 %0, %1, %2" : "=v"(p1.x) : "v"(a2[cur].x), "v"(a2[cur].y));
            asm("v_cvt_pk_bf16_f32 %0, %1, %2" : "=v"(p1.y) : "v"(a2[cur].z), "v"(a2[cur].w));
            asm("v_cvt_pk_bf16_f32 %0, %1, %2" : "=v"(p1.z) : "v"(a3[cur].x), "v"(a3[cur].y));
            asm("v_cvt_pk_bf16_f32 %0, %1, %2" : "=v"(p1.w) : "v"(a3[cur].z), "v"(a3[cur].w));
            af0 = *(const s16x8*)&p0;
            af1 = *(const s16x8*)&p1;
        }
        #pragma unroll
        for (int j = 0; j < 8; ++j) {
            acc[0][j] = __builtin_amdgcn_mfma_f32_16x16x32_bf16(af0, wf[cur][j], acc[0][j], 0, 0, 0);
            acc[1][j] = __builtin_amdgcn_mfma_f32_16x16x32_bf16(af1, wf[cur][j], acc[1][j], 0, 0, 0);
        }
        if ((kc & 3) == 3 && kc != 15) soft_barrier();   // bound wave drift (L2 locality)
    }
#undef S1_ISSUE

    // epilogue: H = relu(acc + b1) -> Hbuf.  D layout: col=lane&15, row=(lane>>4)*4+r
    //   row = wr*32 + i*16 + (lane>>4)*4 + r ; col = wc*128 + j*16 + l15
    #pragma unroll
    for (int j = 0; j < 8; ++j) {
        int col = wc * 128 + j * 16 + l15;
        float bb = b1[col];
        #pragma unroll
        for (int i = 0; i < 2; ++i) {
            #pragma unroll
            for (int r = 0; r < 4; ++r) {
                int row = wr * 32 + i * 16 + (lane >> 4) * 4 + r;
                Hbuf[row][col] = f2bf(fmaxf(acc[i][j][r] + bb, 0.f));
            }
        }
    }
    __syncthreads();   // Hbuf visible to all waves

    // ========== link column: lc_k = h_k . Wf[:,256]  (wave wid owns position wid) ==========
    float wl0 = Wf[(lane * 4 + 0) * 257 + 256];
    float wl1 = Wf[(lane * 4 + 1) * 257 + 256];
    float wl2 = Wf[(lane * 4 + 2) * 257 + 256];
    float wl3 = Wf[(lane * 4 + 3) * 257 + 256];
    float bf256 = bfv[256];

    float lcreg = 0.f;
    for (int k = 0; k < 16; ++k) {
        ushort4 hv = *(const ushort4*)&Hbuf[wid * 16 + k][lane * 4];
        float p = bf2f(hv.x) * wl0 + bf2f(hv.y) * wl1 + bf2f(hv.z) * wl2 + bf2f(hv.w) * wl3;
        #pragma unroll
        for (int off = 32; off > 0; off >>= 1) p += __shfl_xor(p, off, 64);
        if (lane == k) lcreg = p;
    }

    // ========== weights: w_k, ww_k = w_k*m_k, s, updates_256 ==========
    float wwreg = 0.f;
    float u256 = 0.f;
    if (lane < 16) {
        float mv  = mg[(blk * 8 + wid) * 16 + lane];
        float raw = lcreg + bf256;
        float sg  = 1.f / (1.f + expf(-raw));
        float v   = mv * sg;
        float lw  = v + 1e-8f;
        float nrm = lw;
        #pragma unroll
        for (int off = 8; off > 0; off >>= 1) nrm += __shfl_xor(nrm, off, 16);
        float wk = lw / nrm;
        wwreg = wk * mv;
        float u = wk * v;
        float s = wwreg;
        #pragma unroll
        for (int off = 8; off > 0; off >>= 1) {
            u += __shfl_xor(u, off, 16);
            s += __shfl_xor(s, off, 16);
        }
        u256 = u;
        if (lane == 0) sbuf[wid] = s;
    }
    u256 = __shfl(u256, 0, 64);   // broadcast to all 64 lanes of this wave

    // ========== g_p = sum_k ww_k * h_k  -> gbuf (bf16), rows 8..15 zero ==========
    {
        float ga0 = 0.f, ga1 = 0.f, ga2 = 0.f, ga3 = 0.f;
        #pragma unroll
        for (int k = 0; k < 16; ++k) {
            float wwk = __shfl(wwreg, k, 64);
            ushort4 hv = *(const ushort4*)&Hbuf[wid * 16 + k][lane * 4];
            ga0 += wwk * bf2f(hv.x);
            ga1 += wwk * bf2f(hv.y);
            ga2 += wwk * bf2f(hv.z);
            ga3 += wwk * bf2f(hv.w);
        }
        ushort4 gw; gw.x = f2bf(ga0); gw.y = f2bf(ga1); gw.z = f2bf(ga2); gw.w = f2bf(ga3);
        *(ushort4*)&gbuf[wid][lane * 4] = gw;
        ushort4 z4; z4.x = 0; z4.y = 0; z4.z = 0; z4.w = 0;
        *(ushort4*)&gbuf[8 + wid][lane * 4] = z4;
    }
    __syncthreads();   // gbuf ready

    // ========== GEMM2': updates[:, :256] = g @ Wf[:, :256] — B from L2, ZERO barriers ==========
    f32x4 acc2[2];
    acc2[0] = zero4; acc2[1] = zero4;
    {
        const int w2n0 = ((wid * 2 + 0) * 16 + l15) * 32 + g8;
        const int w2n1 = ((wid * 2 + 1) * 16 + l15) * 32 + g8;
        s16x8 w2a[2], w2b[2];
        w2a[0] = *(const s16x8*)(WfT + w2n0);
        w2b[0] = *(const s16x8*)(WfT + w2n1);
        #pragma unroll
        for (int c2 = 0; c2 < 8; ++c2) {
            const int cur = c2 & 1;
            s16x8 ba = w2a[cur], bb = w2b[cur];
            if (c2 < 7) {
                w2a[cur ^ 1] = *(const s16x8*)(WfT + (c2 + 1) * 8192 + w2n0);
                w2b[cur ^ 1] = *(const s16x8*)(WfT + (c2 + 1) * 8192 + w2n1);
            }
            s16x8 ga = *(const s16x8*)&gbuf[l15][c2 * 32 + g8];
            acc2[0] = __builtin_amdgcn_mfma_f32_16x16x32_bf16(ga, ba, acc2[0], 0, 0, 0);
            acc2[1] = __builtin_amdgcn_mfma_f32_16x16x32_bf16(ga, bb, acc2[1], 0, 0, 0);
        }
    }

    // updates -> LDS (rows 0..7 valid)
    {
        int gq = lane >> 4;   // 0..3 ; D rows gq*4+r, only rows 0..7 are positions
        if (gq < 2) {
            #pragma unroll
            for (int t = 0; t < 2; ++t) {
                int col = (wid * 2 + t) * 16 + l15;
                float bfc = bfv[col];
                #pragma unroll
                for (int r = 0; r < 4; ++r) {
                    int p = gq * 4 + r;
                    updb[p][col] = acc2[t][r] + sbuf[p] * bfc;
                }
            }
        }
    }
    __syncthreads();

    // ========== embeds update + LayerNorm (wave wid owns position wid) ==========
    {
        int base = (blk * 8 + wid) * 256;
        float4 up = *(const float4*)&updb[wid][lane * 4];
        float4 em = *(const float4*)&embeds[base + lane * 4];
        float e0 = em.x + u256 * up.x;
        float e1 = em.y + u256 * up.y;
        float e2 = em.z + u256 * up.z;
        float e3 = em.w + u256 * up.w;
        float s1 = e0 + e1 + e2 + e3;
        float s2 = e0 * e0 + e1 * e1 + e2 * e2 + e3 * e3;
        #pragma unroll
        for (int off = 32; off > 0; off >>= 1) {
            s1 += __shfl_xor(s1, off, 64);
            s2 += __shfl_xor(s2, off, 64);
        }
        float mu  = s1 * (1.f / 256.f);
        float var = s2 * (1.f / 256.f) - mu * mu;
        float rs  = rsqrtf(var + 1e-5f);
        float4 gm = *(const float4*)&gam[lane * 4];
        float4 bt = *(const float4*)&bet[lane * 4];
        float4 o;
        o.x = (e0 - mu) * rs * gm.x + bt.x;
        o.y = (e1 - mu) * rs * gm.y + bt.y;
        o.z = (e2 - mu) * rs * gm.z + bt.z;
        o.w = (e3 - mu) * rs * gm.w + bt.w;
        *(float4*)&out[base + lane * 4] = o;
    }
}

extern "C" void kernel_launch(void* const* d_in, const int* in_sizes, int n_in,
                              void* d_out, int out_size, void* d_ws, size_t ws_size,
                              hipStream_t stream) {
    (void)in_sizes; (void)n_in; (void)ws_size; (void)out_size;
    const float* net_in = (const float*)d_in[0];
    const float* embeds = (const float*)d_in[1];
    const float* mg     = (const float*)d_in[2];
    const float* W1     = (const float*)d_in[3];
    const float* b1     = (const float*)d_in[4];
    const float* Wf     = (const float*)d_in[5];
    const float* bfv    = (const float*)d_in[6];
    const float* gam    = (const float*)d_in[7];
    const float* bet    = (const float*)d_in[8];
    float* outp = (float*)d_out;

    unsigned short* W1T = (unsigned short*)d_ws;                 // 16*256*32 = 131072 elems
    unsigned short* WfT = W1T + 131072;                          //  8*256*32 =  65536 elems

    prep_weights<<<512, 256, 0, stream>>>(W1, Wf, W1T, WfT);
    fused_embed<<<NBLK, 512, 0, stream>>>(net_in, embeds, mg, W1, b1, Wf, bfv, gam, bet, outp, W1T, WfT);
}

// Round 11
// 198.043 us; speedup vs baseline: 1.6760x; 1.6760x over previous
//
#include <hip/hip_runtime.h>

typedef short s16x8 __attribute__((ext_vector_type(8)));
typedef float f32x4 __attribute__((ext_vector_type(4)));

__device__ __forceinline__ unsigned short f2bf(float f) {
    union { float f; unsigned u; } v; v.f = f;
    return (unsigned short)((v.u + 0x7FFFu + ((v.u >> 16) & 1u)) >> 16);
}
__device__ __forceinline__ float bf2f(unsigned short h) {
    union { unsigned u; float f; } v; v.u = ((unsigned)h) << 16;
    return v.f;
}

// LDS-only barrier: does NOT drain vmcnt, so register prefetch loads stay in
// flight across it. sched_barrier(0) fences compiler motion (rule #18).
__device__ __forceinline__ void wg_barrier_lds() {
    __builtin_amdgcn_sched_barrier(0);
    asm volatile("s_waitcnt lgkmcnt(0)" ::: "memory");
    __builtin_amdgcn_s_barrier();
    __builtin_amdgcn_sched_barrier(0);
}

#define NBLK 1024   // 16384 positions / 16 per block

// ---------- prep: W1 (512x256 f32) -> W1T bf16 [16][256][32]; Wf -> WfT bf16 [8][256][32] ----------
__global__ void prep_weights(const float* __restrict__ W1, const float* __restrict__ Wf,
                             unsigned short* __restrict__ W1T, unsigned short* __restrict__ WfT) {
    int t = blockIdx.x * 256 + threadIdx.x;      // 131072 threads
    {   // W1T[t]: t = ((c*256)+n)*32 + kk
        int c  = t >> 13;
        int n  = (t >> 5) & 255;
        int kk = t & 31;
        W1T[t] = f2bf(W1[(c * 32 + kk) * 256 + n]);
    }
    if (t < 65536) {
        int c  = t >> 13;
        int n  = (t >> 5) & 255;
        int hh = t & 31;
        WfT[t] = f2bf(Wf[(c * 32 + hh) * 257 + n]);
    }
}

// 1024 threads = 16 waves = 4 waves/SIMD. LDS 124736 B GUARANTEES 1 block/CU
// (multi-block co-residency is out-of-envelope: failed 5/5 across structures).
__global__ __launch_bounds__(1024)
void fused_embed(const float* __restrict__ net_in, const float* __restrict__ embeds,
                 const float* __restrict__ mg, const float* __restrict__ W1,
                 const float* __restrict__ b1, const float* __restrict__ Wf,
                 const float* __restrict__ bfv, const float* __restrict__ gam,
                 const float* __restrict__ bet, float* __restrict__ out,
                 const unsigned short* __restrict__ W1T, const unsigned short* __restrict__ WfT)
{
    // LDS: 32768 + 66560 + 8448 + 16896 + 64 = 124736 B -> 1 block/CU
    __shared__ unsigned short Abuf[2][256][32];   // net_in chunk, bf16, unpadded (64B rows)
    __shared__ unsigned short Hbuf[128][260];     // HALF of H (128 rows), reused for both halves
    __shared__ unsigned short gbuf[16][264];      // g rows: 16 positions, all real
    __shared__ float updb[16][264];               // updates (16 positions x 256), f32
    __shared__ float sbuf[16];                    // s_p = sum_k w_k m_k

    const int tid  = threadIdx.x;
    const int lane = tid & 63;
    const int wid  = tid >> 6;     // 0..15
    const int wr   = wid >> 2;     // 0..3 (row group: 64 rows)
    const int wc   = wid & 3;      // 0..3 (col group: 64 cols)
    const int l15  = lane & 15;
    const int g8   = (lane >> 4) * 8;
    const int blk  = blockIdx.x;
    const int row0 = blk * 256;

    const f32x4 zero4 = {0.f, 0.f, 0.f, 0.f};

    // ================= GEMM1: H = relu(net_in @ W1 + b1), M=256 =================
    f32x4 acc[4][4];
    #pragma unroll
    for (int i = 0; i < 4; ++i)
        #pragma unroll
        for (int j = 0; j < 4; ++j)
            acc[i][j] = zero4;

    const int ar = tid >> 2;          // A-staging row this thread owns (0..255)
    const int ac = (tid & 3) * 8;     // A-staging col group (8 f32)
    const int wbase = (wc * 64 + l15) * 32 + g8;   // W-fragment base (shorts) within a chunk

    // A: distance-2, two register slots. W: JIT per-iteration (L2-hot, saves VGPR).
    float4 vaA[2], vbA[2];

#define A_ISSUE(KC, S) do { \
        const float* _src = &net_in[(row0 + ar) * 512 + (KC) * 32 + ac]; \
        vaA[S] = *(const float4*)_src; \
        vbA[S] = *(const float4*)(_src + 4); \
    } while (0)

#define A_WRITE(KC, S) do { \
        int4 _pk; \
        asm("v_cvt_pk_bf16_f32 %0, %1, %2" : "=v"(_pk.x) : "v"(vaA[S].x), "v"(vaA[S].y)); \
        asm("v_cvt_pk_bf16_f32 %0, %1, %2" : "=v"(_pk.y) : "v"(vaA[S].z), "v"(vaA[S].w)); \
        asm("v_cvt_pk_bf16_f32 %0, %1, %2" : "=v"(_pk.z) : "v"(vbA[S].x), "v"(vbA[S].y)); \
        asm("v_cvt_pk_bf16_f32 %0, %1, %2" : "=v"(_pk.w) : "v"(vbA[S].z), "v"(vbA[S].w)); \
        *(int4*)&Abuf[(KC) & 1][ar][ac] = _pk; \
    } while (0)

    // prologue: A chunks 0 and 1 in flight; chunk 0 written
    A_ISSUE(0, 0);
    A_ISSUE(1, 1);
    A_WRITE(0, 0);
    wg_barrier_lds();

    #pragma unroll
    for (int kc = 0; kc < 16; ++kc) {
        const int cur = kc & 1;
        // W fragments for THIS chunk, JIT from L2 (prep layout: one 16B load each)
        const unsigned short* wp = W1T + kc * 8192 + wbase;
        s16x8 b0 = *(const s16x8*)(wp);
        s16x8 b1r = *(const s16x8*)(wp + 512);
        s16x8 b2 = *(const s16x8*)(wp + 1024);
        s16x8 b3 = *(const s16x8*)(wp + 1536);
        // issue A chunk kc+2 into the register slot freed last iteration
        if (kc < 14) A_ISSUE(kc + 2, cur);
        // write A chunk kc+1 (loads issued at kc-1 -> a full iteration of cover)
        if (kc < 15) A_WRITE(kc + 1, (kc + 1) & 1);
        // A fragments + 16 MFMAs
        s16x8 af[4];
        #pragma unroll
        for (int i = 0; i < 4; ++i)
            af[i] = *(const s16x8*)&Abuf[cur][wr * 64 + i * 16 + l15][g8];
        #pragma unroll
        for (int i = 0; i < 4; ++i) {
            acc[i][0] = __builtin_amdgcn_mfma_f32_16x16x32_bf16(af[i], b0, acc[i][0], 0, 0, 0);
            acc[i][1] = __builtin_amdgcn_mfma_f32_16x16x32_bf16(af[i], b1r, acc[i][1], 0, 0, 0);
            acc[i][2] = __builtin_amdgcn_mfma_f32_16x16x32_bf16(af[i], b2, acc[i][2], 0, 0, 0);
            acc[i][3] = __builtin_amdgcn_mfma_f32_16x16x32_bf16(af[i], b3, acc[i][3], 0, 0, 0);
        }
        wg_barrier_lds();
    }
#undef A_ISSUE
#undef A_WRITE

    // ================= tail: two halves over a shared 128-row Hbuf =================
    float wl0 = Wf[(lane * 4 + 0) * 257 + 256];
    float wl1 = Wf[(lane * 4 + 1) * 257 + 256];
    float wl2 = Wf[(lane * 4 + 2) * 257 + 256];
    float wl3 = Wf[(lane * 4 + 3) * 257 + 256];
    float bf256 = bfv[256];

    float u256 = 0.f;   // set in this wave's half

    #pragma unroll
    for (int h = 0; h < 2; ++h) {
        const int mine = ((wid >> 3) == h);   // waves h*8..h*8+7 own this half

        // epilogue: H = relu(acc + b1) for rows [h*128, h*128+128) -> Hbuf
        // D layout: row = wr*64 + i*16 + (lane>>4)*4 + r ; col = wc*64 + j*16 + l15
        if (mine) {
            #pragma unroll
            for (int j = 0; j < 4; ++j) {
                int col = wc * 64 + j * 16 + l15;
                float bb = b1[col];
                #pragma unroll
                for (int i = 0; i < 4; ++i) {
                    #pragma unroll
                    for (int r = 0; r < 4; ++r) {
                        int rih = (wr & 1) * 64 + i * 16 + (lane >> 4) * 4 + r;
                        Hbuf[rih][col] = f2bf(fmaxf(acc[i][j][r] + bb, 0.f));
                    }
                }
            }
        }
        __syncthreads();   // Hbuf(half h) visible

        if (mine) {
            // ===== link column: lc_k = h_k . Wf[:,256] (wave wid owns position wid) =====
            float lcreg = 0.f;
            for (int k = 0; k < 16; ++k) {
                ushort4 hv = *(const ushort4*)&Hbuf[(wid & 7) * 16 + k][lane * 4];
                float p = bf2f(hv.x) * wl0 + bf2f(hv.y) * wl1 + bf2f(hv.z) * wl2 + bf2f(hv.w) * wl3;
                #pragma unroll
                for (int off = 32; off > 0; off >>= 1) p += __shfl_xor(p, off, 64);
                if (lane == k) lcreg = p;
            }

            // ===== softmax weights =====
            float wwreg = 0.f;
            if (lane < 16) {
                float mv  = mg[(blk * 16 + wid) * 16 + lane];
                float raw = lcreg + bf256;
                float sg  = 1.f / (1.f + expf(-raw));
                float v   = mv * sg;
                float lw  = v + 1e-8f;
                float nrm = lw;
                #pragma unroll
                for (int off = 8; off > 0; off >>= 1) nrm += __shfl_xor(nrm, off, 16);
                float wk = lw / nrm;
                wwreg = wk * mv;
                float u = wk * v;
                float s = wwreg;
                #pragma unroll
                for (int off = 8; off > 0; off >>= 1) {
                    u += __shfl_xor(u, off, 16);
                    s += __shfl_xor(s, off, 16);
                }
                u256 = u;
                if (lane == 0) sbuf[wid] = s;
            }
            u256 = __shfl(u256, 0, 64);

            // ===== g_p = sum_k ww_k h_k -> gbuf row wid =====
            float ga0 = 0.f, ga1 = 0.f, ga2 = 0.f, ga3 = 0.f;
            #pragma unroll
            for (int k = 0; k < 16; ++k) {
                float wwk = __shfl(wwreg, k, 64);
                ushort4 hv = *(const ushort4*)&Hbuf[(wid & 7) * 16 + k][lane * 4];
                ga0 += wwk * bf2f(hv.x);
                ga1 += wwk * bf2f(hv.y);
                ga2 += wwk * bf2f(hv.z);
                ga3 += wwk * bf2f(hv.w);
            }
            ushort4 gw; gw.x = f2bf(ga0); gw.y = f2bf(ga1); gw.z = f2bf(ga2); gw.w = f2bf(ga3);
            *(ushort4*)&gbuf[wid][lane * 4] = gw;
        }
        __syncthreads();   // half-h Hbuf reads done (safe to overwrite) + gbuf rows landed
    }

    // ========== GEMM2': updates = g @ Wf[:, :256] — 16 waves x 1 col-tile, B from L2 ==========
    f32x4 acc2 = zero4;
    {
        const int n0 = (wid * 16 + l15) * 32 + g8;
        s16x8 w2[2];
        w2[0] = *(const s16x8*)(WfT + n0);
        #pragma unroll
        for (int c2 = 0; c2 < 8; ++c2) {
            const int cur = c2 & 1;
            s16x8 bw = w2[cur];
            if (c2 < 7) w2[cur ^ 1] = *(const s16x8*)(WfT + (c2 + 1) * 8192 + n0);
            s16x8 ga = *(const s16x8*)&gbuf[l15][c2 * 32 + g8];
            acc2 = __builtin_amdgcn_mfma_f32_16x16x32_bf16(ga, bw, acc2, 0, 0, 0);
        }
    }

    // updates -> LDS (all 16 D-rows are real positions now)
    {
        int gq = lane >> 4;
        int col = wid * 16 + l15;
        float bfc = bfv[col];
        #pragma unroll
        for (int r = 0; r < 4; ++r) {
            int p = gq * 4 + r;
            updb[p][col] = acc2[r] + sbuf[p] * bfc;
        }
    }
    __syncthreads();

    // ========== embeds update + LayerNorm (wave wid owns position wid) ==========
    {
        int base = (blk * 16 + wid) * 256;
        float4 up = *(const float4*)&updb[wid][lane * 4];
        float4 em = *(const float4*)&embeds[base + lane * 4];
        float e0 = em.x + u256 * up.x;
        float e1 = em.y + u256 * up.y;
        float e2 = em.z + u256 * up.z;
        float e3 = em.w + u256 * up.w;
        float s1 = e0 + e1 + e2 + e3;
        float s2 = e0 * e0 + e1 * e1 + e2 * e2 + e3 * e3;
        #pragma unroll
        for (int off = 32; off > 0; off >>= 1) {
            s1 += __shfl_xor(s1, off, 64);
            s2 += __shfl_xor(s2, off, 64);
        }
        float mu  = s1 * (1.f / 256.f);
        float var = s2 * (1.f / 256.f) - mu * mu;
        float rs  = rsqrtf(var + 1e-5f);
        float4 gm = *(const float4*)&gam[lane * 4];
        float4 bt = *(const float4*)&bet[lane * 4];
        float4 o;
        o.x = (e0 - mu) * rs * gm.x + bt.x;
        o.y = (e1 - mu) * rs * gm.y + bt.y;
        o.z = (e2 - mu) * rs * gm.z + bt.z;
        o.w = (e3 - mu) * rs * gm.w + bt.w;
        *(float4*)&out[base + lane * 4] = o;
    }
}

extern "C" void kernel_launch(void* const* d_in, const int* in_sizes, int n_in,
                              void* d_out, int out_size, void* d_ws, size_t ws_size,
                              hipStream_t stream) {
    (void)in_sizes; (void)n_in; (void)ws_size; (void)out_size;
    const float* net_in = (const float*)d_in[0];
    const float* embeds = (const float*)d_in[1];
    const float* mg     = (const float*)d_in[2];
    const float* W1     = (const float*)d_in[3];
    const float* b1     = (const float*)d_in[4];
    const float* Wf     = (const float*)d_in[5];
    const float* bfv    = (const float*)d_in[6];
    const float* gam    = (const float*)d_in[7];
    const float* bet    = (const float*)d_in[8];
    float* outp = (float*)d_out;

    unsigned short* W1T = (unsigned short*)d_ws;                 // 16*256*32 = 131072 elems
    unsigned short* WfT = W1T + 131072;                          //  8*256*32 =  65536 elems

    prep_weights<<<512, 256, 0, stream>>>(W1, Wf, W1T, WfT);
    fused_embed<<<NBLK, 1024, 0, stream>>>(net_in, embeds, mg, W1, b1, Wf, bfv, gam, bet, outp, W1T, WfT);
}